// Round 1
// baseline (331.017 us; speedup 1.0000x reference)
//
#include <hip/hip_runtime.h>
#include <math.h>

// x: [B=32, T=2048, H=512] fp32, alpha: [H, 3] fp32 -> out [B, T, H] fp32
// out[b,t,h] = sum_w softmax(alpha[h])[w] * (x - mu_w)/sd_w  (sliding window over t,
// replicate-padded at front, unbiased std, sd clamped at 1e-4).

#define BB 32
#define TT 2048
#define HH 512
#define CHUNK 128   // 16 chunks; grid = 16 x (H/256) x B = 1024 blocks

__global__ __launch_bounds__(256) void fan_kernel(const float* __restrict__ x,
                                                  const float* __restrict__ alpha,
                                                  float* __restrict__ out) {
    const int tid = threadIdx.x;
    const int t0  = blockIdx.x * CHUNK;
    const int h   = blockIdx.y * 256 + tid;
    const int b   = blockIdx.z;

    constexpr int   W[3]       = {5, 10, 20};
    constexpr float INV_W[3]   = {1.0f/5.0f, 1.0f/10.0f, 1.0f/20.0f};
    constexpr float INV_WM1[3] = {1.0f/4.0f, 1.0f/9.0f,  1.0f/19.0f};

    // per-feature softmax over the 3 windows
    float a0 = alpha[h*3+0], a1 = alpha[h*3+1], a2 = alpha[h*3+2];
    float mx = fmaxf(a0, fmaxf(a1, a2));
    float e0 = __expf(a0 - mx), e1 = __expf(a1 - mx), e2 = __expf(a2 - mx);
    float inv_s = 1.0f / (e0 + e1 + e2);
    const float aw[3] = {e0 * inv_s, e1 * inv_s, e2 * inv_s};

    const float* __restrict__ px = x   + ((size_t)b * TT) * HH + h;
    float*       __restrict__ po = out + ((size_t)b * TT) * HH + h;

    if (t0 == 0) {
        // ---- first chunk: build replicate stats (window [0, w-1]) via pre-scan
        float Sw[3], S2w[3];
        {
            float P = 0.f, P2 = 0.f;
            #pragma unroll
            for (int t = 0; t < 20; ++t) {
                float v = px[(size_t)t * HH];
                P += v; P2 += v * v;
                if (t == 4)  { Sw[0] = P; S2w[0] = P2; }
                if (t == 9)  { Sw[1] = P; S2w[1] = P2; }
                if (t == 19) { Sw[2] = P; S2w[2] = P2; }
            }
        }
        float rep_mu[3], rep_rsd[3];
        #pragma unroll
        for (int i = 0; i < 3; ++i) {
            float mu  = Sw[i] * INV_W[i];
            float var = fmaxf((S2w[i] - Sw[i] * mu) * INV_WM1[i], 0.0f);
            rep_mu[i]  = mu;
            rep_rsd[i] = fminf(__builtin_amdgcn_rsqf(var), 1e4f);
        }
        // ---- main loop, windows clipped at t=0
        float S[3]  = {0.f, 0.f, 0.f};
        float S2[3] = {0.f, 0.f, 0.f};
        for (int t = 0; t < CHUNK; ++t) {
            float v  = px[(size_t)t * HH];
            float v2 = v * v;
            float acc = 0.f;
            #pragma unroll
            for (int i = 0; i < 3; ++i) {
                S[i] += v; S2[i] += v2;
                if (t >= W[i]) {
                    float o = px[(size_t)(t - W[i]) * HH];
                    S[i] -= o; S2[i] -= o * o;
                }
                float mu, rsd;
                if (t >= W[i] - 1) {
                    mu = S[i] * INV_W[i];
                    float var = fmaxf((S2[i] - S[i] * mu) * INV_WM1[i], 0.0f);
                    rsd = fminf(__builtin_amdgcn_rsqf(var), 1e4f);
                } else {
                    mu = rep_mu[i]; rsd = rep_rsd[i];
                }
                acc = fmaf((v - mu) * rsd, aw[i], acc);
            }
            po[(size_t)t * HH] = acc;
        }
    } else {
        // ---- interior chunk (t0 >= 20): warm-up sums over [t0-w, t0-1]
        float S[3]  = {0.f, 0.f, 0.f};
        float S2[3] = {0.f, 0.f, 0.f};
        #pragma unroll
        for (int k = 1; k <= 20; ++k) {
            float v = px[(size_t)(t0 - k) * HH];
            float v2 = v * v;
            #pragma unroll
            for (int i = 0; i < 3; ++i)
                if (k <= W[i]) { S[i] += v; S2[i] += v2; }
        }
        for (int t = t0; t < t0 + CHUNK; ++t) {
            float v  = px[(size_t)t * HH];
            float v2 = v * v;
            float acc = 0.f;
            #pragma unroll
            for (int i = 0; i < 3; ++i) {
                float o = px[(size_t)(t - W[i]) * HH];
                S[i]  += v  - o;
                S2[i] += v2 - o * o;
                float mu  = S[i] * INV_W[i];
                float var = fmaxf((S2[i] - S[i] * mu) * INV_WM1[i], 0.0f);
                float rsd = fminf(__builtin_amdgcn_rsqf(var), 1e4f);
                acc = fmaf((v - mu) * rsd, aw[i], acc);
            }
            po[(size_t)t * HH] = acc;
        }
    }
}

extern "C" void kernel_launch(void* const* d_in, const int* in_sizes, int n_in,
                              void* d_out, int out_size, void* d_ws, size_t ws_size,
                              hipStream_t stream) {
    const float* x     = (const float*)d_in[0];
    const float* alpha = (const float*)d_in[1];
    float*       out   = (float*)d_out;

    dim3 grid(TT / CHUNK, HH / 256, BB);  // 16 x 2 x 32 = 1024 blocks
    dim3 block(256);
    fan_kernel<<<grid, block, 0, stream>>>(x, alpha, out);
}

// Round 2
// 270.387 us; speedup vs baseline: 1.2242x; 1.2242x over previous
//
#include <hip/hip_runtime.h>
#include <math.h>

// x: [B=32, T=2048, H=512] fp32, alpha: [H,3] -> out [B,T,H] fp32.
// Per-feature softmax blend of 3 sliding-window z-scores (w=5,10,20),
// replicate-padded at front, unbiased std, sd clamped at 1e-4.
//
// Layout: one thread per float4 column (H/4=128), block=128 threads (2 waves),
// grid = (T/CHUNK) x B. Group-of-4 load batching for memory-level parallelism.

#define BB 32
#define TT 2048
#define HH 512
#define H4 128      // HH/4
#define CHUNK 32    // T-chunk per block; 64 chunks x 32 B = 2048 blocks

__global__ __launch_bounds__(128) void fan_kernel(const float* __restrict__ x,
                                                  const float* __restrict__ alpha,
                                                  float* __restrict__ out) {
    const int c  = threadIdx.x;            // float4 column 0..127
    const int t0 = blockIdx.x * CHUNK;
    const int b  = blockIdx.y;

    constexpr int   W[3]       = {5, 10, 20};
    constexpr float INV_W[3]   = {0.2f, 0.1f, 0.05f};
    constexpr float INV_WM1[3] = {0.25f, 1.0f/9.0f, 1.0f/19.0f};

    // softmax over the 3 windows for this thread's 4 channels
    float aw[3][4];
    {
        const float4* a4 = (const float4*)alpha + 3 * c;  // 12 contiguous floats
        float4 A0 = a4[0], A1 = a4[1], A2 = a4[2];
        float f[12] = {A0.x,A0.y,A0.z,A0.w, A1.x,A1.y,A1.z,A1.w, A2.x,A2.y,A2.z,A2.w};
        #pragma unroll
        for (int j = 0; j < 4; ++j) {
            float b0 = f[3*j], b1 = f[3*j+1], b2 = f[3*j+2];
            float mx = fmaxf(b0, fmaxf(b1, b2));
            float e0 = __expf(b0-mx), e1 = __expf(b1-mx), e2 = __expf(b2-mx);
            float inv = 1.0f / (e0 + e1 + e2);
            aw[0][j] = e0*inv; aw[1][j] = e1*inv; aw[2][j] = e2*inv;
        }
    }

    const float4* __restrict__ px = (const float4*)x + (size_t)b * TT * H4 + c;
    float4*       __restrict__ po = (float4*)out     + (size_t)b * TT * H4 + c;

    float S[3][4], S2[3][4];
    #pragma unroll
    for (int i = 0; i < 3; ++i)
        #pragma unroll
        for (int j = 0; j < 4; ++j) { S[i][j] = 0.f; S2[i][j] = 0.f; }

    int tstart;

    if (t0 == 0) {
        // ---- prescan [0,20): prefix checkpoints at t-counts 5,10,15,20
        float P[4] = {0,0,0,0}, P2[4] = {0,0,0,0};
        float CP[4][4], CQ[4][4];
        #pragma unroll
        for (int t = 0; t < 20; ++t) {
            float4 V = px[(size_t)t * H4];
            float v[4] = {V.x, V.y, V.z, V.w};
            #pragma unroll
            for (int j = 0; j < 4; ++j) { P[j] += v[j]; P2[j] += v[j]*v[j]; }
            if (t == 4 || t == 9 || t == 14 || t == 19) {
                const int ci = (t + 1) / 5 - 1;
                #pragma unroll
                for (int j = 0; j < 4; ++j) { CP[ci][j] = P[j]; CQ[ci][j] = P2[j]; }
            }
        }
        // replicate stats: window [0, w-1] -> checkpoints 5,10,20 (idx 0,1,3)
        float rmu[3][4], rrsd[3][4];
        constexpr int CMAP[3] = {0, 1, 3};
        #pragma unroll
        for (int i = 0; i < 3; ++i)
            #pragma unroll
            for (int j = 0; j < 4; ++j) {
                float s = CP[CMAP[i]][j], s2 = CQ[CMAP[i]][j];
                float mu  = s * INV_W[i];
                float var = fmaxf((s2 - s*mu) * INV_WM1[i], 0.f);
                rmu[i][j]  = mu;
                rrsd[i][j] = fminf(__builtin_amdgcn_rsqf(var), 1e4f);
            }
        // ---- output loop [0,20), running sums (fully unrolled: branches static)
        #pragma unroll
        for (int t = 0; t < 20; ++t) {
            float4 V = px[(size_t)t * H4];
            float v[4] = {V.x, V.y, V.z, V.w};
            float acc[4] = {0,0,0,0};
            #pragma unroll
            for (int i = 0; i < 3; ++i) {
                if (t >= W[i]) {
                    float4 O = px[(size_t)(t - W[i]) * H4];
                    float o[4] = {O.x, O.y, O.z, O.w};
                    #pragma unroll
                    for (int j = 0; j < 4; ++j) {
                        S[i][j]  += v[j] - o[j];
                        S2[i][j] += v[j]*v[j] - o[j]*o[j];
                    }
                } else {
                    #pragma unroll
                    for (int j = 0; j < 4; ++j) {
                        S[i][j]  += v[j];
                        S2[i][j] += v[j]*v[j];
                    }
                }
                #pragma unroll
                for (int j = 0; j < 4; ++j) {
                    float mu, rs;
                    if (t >= W[i] - 1) {
                        mu = S[i][j] * INV_W[i];
                        float var = fmaxf((S2[i][j] - S[i][j]*mu) * INV_WM1[i], 0.f);
                        rs = fminf(__builtin_amdgcn_rsqf(var), 1e4f);
                    } else {
                        mu = rmu[i][j]; rs = rrsd[i][j];
                    }
                    acc[j] = fmaf((v[j] - mu) * rs, aw[i][j], acc[j]);
                }
            }
            po[(size_t)t * H4] = make_float4(acc[0], acc[1], acc[2], acc[3]);
        }
        // entry sums for t=20: S_w = P20 - P(20-w)
        #pragma unroll
        for (int j = 0; j < 4; ++j) {
            S[0][j] = CP[3][j] - CP[2][j];  S2[0][j] = CQ[3][j] - CQ[2][j];
            S[1][j] = CP[3][j] - CP[1][j];  S2[1][j] = CQ[3][j] - CQ[1][j];
            S[2][j] = CP[3][j];             S2[2][j] = CQ[3][j];
        }
        tstart = 20;
    } else {
        // ---- interior warm-up: sums over [t0-w, t0-1]
        #pragma unroll
        for (int k = 1; k <= 20; ++k) {
            float4 V = px[(size_t)(t0 - k) * H4];
            float v[4] = {V.x, V.y, V.z, V.w};
            #pragma unroll
            for (int i = 0; i < 3; ++i)
                if (k <= W[i]) {
                    #pragma unroll
                    for (int j = 0; j < 4; ++j) {
                        S[i][j] += v[j]; S2[i][j] += v[j]*v[j];
                    }
                }
        }
        tstart = t0;
    }

    // ---- grouped main loop: batch 16 loads per 4 time-steps, then compute
    const int tend = t0 + CHUNK;
    for (int t = tstart; t < tend; t += 4) {
        float v[4][4], o[4][3][4];
        #pragma unroll
        for (int g = 0; g < 4; ++g) {
            float4 V = px[(size_t)(t + g) * H4];
            v[g][0] = V.x; v[g][1] = V.y; v[g][2] = V.z; v[g][3] = V.w;
        }
        #pragma unroll
        for (int g = 0; g < 4; ++g)
            #pragma unroll
            for (int i = 0; i < 3; ++i) {
                float4 O = px[(size_t)(t + g - W[i]) * H4];
                o[g][i][0] = O.x; o[g][i][1] = O.y; o[g][i][2] = O.z; o[g][i][3] = O.w;
            }
        #pragma unroll
        for (int g = 0; g < 4; ++g) {
            float acc[4] = {0,0,0,0};
            #pragma unroll
            for (int i = 0; i < 3; ++i)
                #pragma unroll
                for (int j = 0; j < 4; ++j) {
                    float vv = v[g][j], oo = o[g][i][j];
                    S[i][j]  += vv - oo;
                    S2[i][j] += vv*vv - oo*oo;
                    float mu  = S[i][j] * INV_W[i];
                    float var = fmaxf((S2[i][j] - S[i][j]*mu) * INV_WM1[i], 0.f);
                    float rs  = fminf(__builtin_amdgcn_rsqf(var), 1e4f);
                    acc[j] = fmaf((vv - mu) * rs, aw[i][j], acc[j]);
                }
            po[(size_t)(t + g) * H4] = make_float4(acc[0], acc[1], acc[2], acc[3]);
        }
    }
}

extern "C" void kernel_launch(void* const* d_in, const int* in_sizes, int n_in,
                              void* d_out, int out_size, void* d_ws, size_t ws_size,
                              hipStream_t stream) {
    const float* x     = (const float*)d_in[0];
    const float* alpha = (const float*)d_in[1];
    float*       out   = (float*)d_out;

    dim3 grid(TT / CHUNK, BB);   // 64 x 32 = 2048 blocks
    dim3 block(128);             // 2 waves: one thread per float4 column
    fan_kernel<<<grid, block, 0, stream>>>(x, alpha, out);
}

// Round 3
// 248.964 us; speedup vs baseline: 1.3296x; 1.0860x over previous
//
#include <hip/hip_runtime.h>
#include <math.h>

// x: [B=32, T=2048, H=512] fp32, alpha: [H,3] -> out [B,T,H] fp32.
// Per-feature softmax blend of 3 sliding-window z-scores (w=5,10,20),
// replicate-padded at front, unbiased std, sd clamped at 1e-4.
//
// R3 design: each x element loaded from HBM exactly once. 20-step history kept
// in a per-thread-private LDS ring (ring[slot][tid]; no barriers needed).
// One thread per float2 column (H/2=256), block=256 threads, CHUNK=64 t-steps.
// Ring = 40 KB/block -> 4 blocks/CU (160 KB LDS) = 16 waves/CU.
// Output written with nontemporal stores (never re-read; keep L2/L3 for x halo).

typedef float v2f __attribute__((ext_vector_type(2)));

#define BB 32
#define TT 2048
#define HH 512
#define H2 256      // HH/2 float2 columns
#define CHUNK 64    // grid = (2048/64=32) x 32 = 1024 blocks

__global__ __launch_bounds__(256) void fan_kernel(const float* __restrict__ x,
                                                  const float* __restrict__ alpha,
                                                  float* __restrict__ out) {
    __shared__ v2f ring[20][H2];   // 40960 B

    const int tid = threadIdx.x;
    const int t0  = blockIdx.x * CHUNK;
    const int b   = blockIdx.y;

    constexpr int   W[3]       = {5, 10, 20};
    constexpr float INV_W[3]   = {0.2f, 0.1f, 0.05f};
    constexpr float INV_WM1[3] = {0.25f, 1.0f/9.0f, 1.0f/19.0f};

    // per-feature softmax over the 3 windows (2 channels per thread)
    float aw[3][2];
    {
        const v2f* a2 = (const v2f*)alpha + 3 * tid;   // 6 contiguous floats
        v2f A0 = a2[0], A1 = a2[1], A2 = a2[2];
        float f[2][3] = {{A0.x, A0.y, A1.x}, {A1.y, A2.x, A2.y}};
        #pragma unroll
        for (int j = 0; j < 2; ++j) {
            float mx = fmaxf(f[j][0], fmaxf(f[j][1], f[j][2]));
            float e0 = __expf(f[j][0] - mx);
            float e1 = __expf(f[j][1] - mx);
            float e2 = __expf(f[j][2] - mx);
            float inv = 1.0f / (e0 + e1 + e2);
            aw[0][j] = e0 * inv; aw[1][j] = e1 * inv; aw[2][j] = e2 * inv;
        }
    }

    const v2f* __restrict__ px = (const v2f*)x + (size_t)b * TT * H2 + tid;
    v2f*       __restrict__ po = (v2f*)out     + (size_t)b * TT * H2 + tid;

    float S[3][2], S2[3][2];
    #pragma unroll
    for (int i = 0; i < 3; ++i) { S[i][0]=S[i][1]=0.f; S2[i][0]=S2[i][1]=0.f; }

    int tstart;

    if (t0 == 0) {
        // ---- pass 1: prescan rows [0,20), fill ring, prefix checkpoints at 5,10,15,20
        float P[2] = {0,0}, Q[2] = {0,0};
        float CP[4][2], CQ[4][2];
        #pragma unroll
        for (int t = 0; t < 20; ++t) {
            v2f V = px[(size_t)t * H2];
            ring[t][tid] = V;
            float v[2] = {V.x, V.y};
            #pragma unroll
            for (int j = 0; j < 2; ++j) { P[j] += v[j]; Q[j] += v[j]*v[j]; }
            if (t == 4 || t == 9 || t == 14 || t == 19) {
                const int ci = (t + 1) / 5 - 1;
                #pragma unroll
                for (int j = 0; j < 2; ++j) { CP[ci][j] = P[j]; CQ[ci][j] = Q[j]; }
            }
        }
        // replicate stats: windows [0,w-1] -> checkpoints 5,10,20 (idx 0,1,3)
        float rmu[3][2], rrsd[3][2];
        constexpr int CMAP[3] = {0, 1, 3};
        #pragma unroll
        for (int i = 0; i < 3; ++i)
            #pragma unroll
            for (int j = 0; j < 2; ++j) {
                float s = CP[CMAP[i]][j], s2 = CQ[CMAP[i]][j];
                float mu  = s * INV_W[i];
                float var = fmaxf((s2 - s*mu) * INV_WM1[i], 0.f);
                rmu[i][j]  = mu;
                rrsd[i][j] = fminf(__builtin_amdgcn_rsqf(var), 1e4f);
            }
        // ---- pass 2: outputs [0,20) from ring (LDS-resident), running clipped sums
        #pragma unroll
        for (int t = 0; t < 20; ++t) {
            v2f V = ring[t][tid];
            float v[2] = {V.x, V.y};
            float acc[2] = {0.f, 0.f};
            #pragma unroll
            for (int i = 0; i < 3; ++i) {
                if (t >= W[i]) {
                    v2f O = ring[t - W[i]][tid];
                    float o[2] = {O.x, O.y};
                    #pragma unroll
                    for (int j = 0; j < 2; ++j) {
                        S[i][j]  += v[j] - o[j];
                        S2[i][j] += v[j]*v[j] - o[j]*o[j];
                    }
                } else {
                    #pragma unroll
                    for (int j = 0; j < 2; ++j) {
                        S[i][j]  += v[j];
                        S2[i][j] += v[j]*v[j];
                    }
                }
                #pragma unroll
                for (int j = 0; j < 2; ++j) {
                    float mu, rs;
                    if (t >= W[i] - 1) {
                        mu = S[i][j] * INV_W[i];
                        float var = fmaxf((S2[i][j] - S[i][j]*mu) * INV_WM1[i], 0.f);
                        rs = fminf(__builtin_amdgcn_rsqf(var), 1e4f);
                    } else {
                        mu = rmu[i][j]; rs = rrsd[i][j];
                    }
                    acc[j] = fmaf((v[j] - mu) * rs, aw[i][j], acc[j]);
                }
            }
            v2f r; r.x = acc[0]; r.y = acc[1];
            __builtin_nontemporal_store(r, &po[(size_t)t * H2]);
        }
        // entry sums for t=20: S_w = P20 - P(20-w)
        #pragma unroll
        for (int j = 0; j < 2; ++j) {
            S[0][j] = CP[3][j] - CP[2][j];  S2[0][j] = CQ[3][j] - CQ[2][j];
            S[1][j] = CP[3][j] - CP[1][j];  S2[1][j] = CQ[3][j] - CQ[1][j];
            S[2][j] = CP[3][j];             S2[2][j] = CQ[3][j];
        }
        tstart = 20;
    } else {
        // ---- interior warm-up: rows [t0-20, t0-1] -> ring + clipped sums
        #pragma unroll
        for (int k = 1; k <= 20; ++k) {
            const int t = t0 - k;
            v2f V = px[(size_t)t * H2];
            ring[t % 20][tid] = V;
            float v[2] = {V.x, V.y};
            #pragma unroll
            for (int i = 0; i < 3; ++i)
                if (k <= W[i]) {
                    #pragma unroll
                    for (int j = 0; j < 2; ++j) {
                        S[i][j] += v[j]; S2[i][j] += v[j]*v[j];
                    }
                }
        }
        tstart = t0;
    }

    // ---- main loop: groups of 4, batched loads; ring slot counters mod 20
    int m0  = tstart % 20;          // slot of x[t-20] == slot to write x[t]
    int m5  = (m0 + 15) % 20;       // slot of x[t-5]
    int m10 = (m0 + 10) % 20;       // slot of x[t-10]

    const int tend = t0 + CHUNK;
    for (int t = tstart; t < tend; t += 4) {
        v2f V[4];
        #pragma unroll
        for (int g = 0; g < 4; ++g) V[g] = px[(size_t)(t + g) * H2];

        #pragma unroll
        for (int g = 0; g < 4; ++g) {
            v2f o20 = ring[m0][tid];      // read delay-20 BEFORE overwrite
            v2f o5  = ring[m5][tid];
            v2f o10 = ring[m10][tid];
            ring[m0][tid] = V[g];

            float v[2]     = {V[g].x, V[g].y};
            float od[3][2] = {{o5.x, o5.y}, {o10.x, o10.y}, {o20.x, o20.y}};
            float acc[2]   = {0.f, 0.f};
            #pragma unroll
            for (int i = 0; i < 3; ++i)
                #pragma unroll
                for (int j = 0; j < 2; ++j) {
                    float vv = v[j], oo = od[i][j];
                    S[i][j]  += vv - oo;
                    S2[i][j] += vv*vv - oo*oo;
                    float mu  = S[i][j] * INV_W[i];
                    float var = fmaxf((S2[i][j] - S[i][j]*mu) * INV_WM1[i], 0.f);
                    float rs  = fminf(__builtin_amdgcn_rsqf(var), 1e4f);
                    acc[j] = fmaf((vv - mu) * rs, aw[i][j], acc[j]);
                }
            v2f r; r.x = acc[0]; r.y = acc[1];
            __builtin_nontemporal_store(r, &po[(size_t)(t + g) * H2]);

            m0  = (m0  == 19) ? 0 : m0  + 1;
            m5  = (m5  == 19) ? 0 : m5  + 1;
            m10 = (m10 == 19) ? 0 : m10 + 1;
        }
    }
}

extern "C" void kernel_launch(void* const* d_in, const int* in_sizes, int n_in,
                              void* d_out, int out_size, void* d_ws, size_t ws_size,
                              hipStream_t stream) {
    const float* x     = (const float*)d_in[0];
    const float* alpha = (const float*)d_in[1];
    float*       out   = (float*)d_out;

    dim3 grid(TT / CHUNK, BB);   // 32 x 32 = 1024 blocks
    dim3 block(256);             // one thread per float2 column of H
    fan_kernel<<<grid, block, 0, stream>>>(x, alpha, out);
}